// Round 19
// baseline (155.096 us; speedup 1.0000x reference)
//
#include <hip/hip_runtime.h>
#include <hip/hip_bf16.h>
#include <stdint.h>

typedef float f32x4 __attribute__((ext_vector_type(4)));
typedef float f32x16 __attribute__((ext_vector_type(16)));
typedef __bf16 bf16x8 __attribute__((ext_vector_type(8)));

#define NBH 64      // B*H
#define SS 1024     // SQ == SKV
#define DAUG 144    // augmented head dim 132 padded to 144
#define KAPPA 0.18033688011104293f  // 0.125 * log2(e), folded into Q~

static __device__ __forceinline__ unsigned short f2b(float f) {
  union { float f; uint32_t u; } v; v.f = f;
  return (unsigned short)((v.u + 0x7fffu + ((v.u >> 16) & 1u)) >> 16);
}
static __device__ __forceinline__ float b2f(unsigned short s) {
  union { uint32_t u; float f; } v; v.u = ((uint32_t)s) << 16;
  return v.f;
}
static __device__ __forceinline__ uint32_t pk2(float a, float b) {
  return (uint32_t)f2b(a) | ((uint32_t)f2b(b) << 16);
}
// HW packed f32->bf16 (RTNE), 1 instr (no builtin on gfx950 - T12 recipe)
static __device__ __forceinline__ uint32_t cvtpk(float lo, float hi) {
  uint32_t r;
  asm("v_cvt_pk_bf16_f32 %0, %1, %2" : "=v"(r) : "v"(lo), "v"(hi));
  return r;
}

static __device__ __forceinline__ void async16(const void* g, void* l) {
  __builtin_amdgcn_global_load_lds(
      (const __attribute__((address_space(1))) uint32_t*)g,
      (__attribute__((address_space(3))) uint32_t*)l, 16, 0, 0);
}

// K-tile chunk swizzle (18 16B-chunks per 144-elem row)
static __device__ __forceinline__ int ksw(int c, int row) {
  return (c < 16) ? (c ^ (row & 7)) : (16 + ((c & 1) ^ (row & 1)));
}

// ---------------- f32 -> bf16 conversion for 7 tensors ----------------
__global__ void convert7(const float* q, const float* k, const float* v,
                         const float* wq, const float* wk, const float* wv, const float* wo,
                         unsigned short* xq, unsigned short* xk, unsigned short* xv,
                         unsigned short* bwq, unsigned short* bwk, unsigned short* bwv,
                         unsigned short* bwo) {
  const float* s; unsigned short* d; int n;
  switch (blockIdx.y) {
    case 0: s = q;  d = xq;  n = 4194304; break;
    case 1: s = k;  d = xk;  n = 4194304; break;
    case 2: s = v;  d = xv;  n = 4194304; break;
    case 3: s = wq; d = bwq; n = 1048576; break;
    case 4: s = wk; d = bwk; n = 1048576; break;
    case 5: s = wv; d = bwv; n = 1048576; break;
    default: s = wo; d = bwo; n = 1048576; break;
  }
  int n4 = n >> 2;
  for (int i = blockIdx.x * blockDim.x + threadIdx.x; i < n4; i += gridDim.x * blockDim.x) {
    float4 f = ((const float4*)s)[i];
    uint2 o;
    o.x = cvtpk(f.x, f.y);
    o.y = cvtpk(f.z, f.w);
    ((uint2*)d)[i] = o;
  }
}

// ---------------- QKV projection GEMM + fused rank-34 augmentation ----------------
// R12 structure + T4 counted-vmcnt triple-buffer: stage(it+2) stays in flight
// across a raw s_barrier; s_waitcnt vmcnt(4) only waits for stage(it+1).
__global__ __launch_bounds__(256) void proj_qkv(
    const unsigned short* __restrict__ Xq, const unsigned short* __restrict__ Xk,
    const unsigned short* __restrict__ Xv, const unsigned short* __restrict__ Wqb,
    const unsigned short* __restrict__ Wkb, const unsigned short* __restrict__ Wvb,
    unsigned short* __restrict__ Qt, unsigned short* __restrict__ Kt,
    unsigned short* __restrict__ Vp, const float* __restrict__ relk,
    const float* __restrict__ relq) {
  const int n_ = blockIdx.x + 32 * (blockIdx.y + 8 * blockIdx.z);
  const int o_ = (n_ & 7) * 96 + (n_ >> 3);
  const int bx = o_ & 31, by = (o_ >> 5) & 7, z = o_ >> 8;

  const unsigned short* A = (z == 0) ? Xq : (z == 1) ? Xk : Xv;
  const unsigned short* Bw = (z == 0) ? Wqb : (z == 1) ? Wkb : Wvb;
  unsigned short* Dst = (z == 0) ? Qt : (z == 1) ? Kt : Vp;
  const int dstride = (z == 2) ? 64 : DAUG;
  const float sc = (z == 0) ? KAPPA : 1.0f;

  __shared__ unsigned short SMEM[24576];  // At 3x4096 + Bt 3x4096 (48KB); Ys reuses [0..16383]
  unsigned short* AtB = SMEM;
  unsigned short* BtB = SMEM + 12288;
  unsigned short* Ys = SMEM;

  const int tid = threadIdx.x, wave = tid >> 6, lane = tid & 63;
  const int r15 = lane & 15, g4 = lane >> 4;
  const int i0 = bx * 128, j0 = by * 128;
  const int wm = (wave >> 1) * 64, wn = (wave & 1) * 64;

  // one stage = 4 vmem instructions per thread (2 A chunks + 2 B chunks)
  auto stage = [&](int it, int buf) {
    int k0 = it * 32;
#pragma unroll
    for (int c = 0; c < 2; ++c) {
      int ch = (wave * 2 + c) * 64 + lane;
      int row = ch >> 2, cg = ch & 3;
      async16(A + (size_t)(i0 + row) * 1024 + k0 + cg * 8, AtB + buf * 4096 + (wave * 2 + c) * 512);
      async16(Bw + (size_t)(j0 + row) * 1024 + k0 + cg * 8, BtB + buf * 4096 + (wave * 2 + c) * 512);
    }
  };

  f32x4 acc[4][4];
#pragma unroll
  for (int m = 0; m < 4; ++m)
#pragma unroll
    for (int n = 0; n < 4; ++n) acc[m][n] = (f32x4){0.f, 0.f, 0.f, 0.f};

  stage(0, 0);
  stage(1, 1);
  asm volatile("s_waitcnt vmcnt(4)" ::: "memory");  // tile 0 landed; tile 1 in flight
  __builtin_amdgcn_s_barrier();

  for (int it = 0; it < 32; ++it) {
    const int cur = it % 3;
    if (it < 30) stage(it + 2, (it + 2) % 3);
    bf16x8 af[4], bf[4];
#pragma unroll
    for (int m = 0; m < 4; ++m)
      af[m] = *(const bf16x8*)(AtB + cur * 4096 + (wm + m * 16 + r15) * 32 + g4 * 8);
#pragma unroll
    for (int n = 0; n < 4; ++n)
      bf[n] = *(const bf16x8*)(BtB + cur * 4096 + (wn + n * 16 + r15) * 32 + g4 * 8);
    __builtin_amdgcn_s_setprio(1);
#pragma unroll
    for (int m = 0; m < 4; ++m)
#pragma unroll
      for (int n = 0; n < 4; ++n)
        acc[m][n] = __builtin_amdgcn_mfma_f32_16x16x32_bf16(af[m], bf[n], acc[m][n], 0, 0, 0);
    __builtin_amdgcn_s_setprio(0);
    // wait for stage(it+1) only; stage(it+2)'s 4 loads stay in flight
    if (it < 30) {
      asm volatile("s_waitcnt vmcnt(4)" ::: "memory");
    } else {
      asm volatile("s_waitcnt vmcnt(0)" ::: "memory");
    }
    __builtin_amdgcn_s_barrier();
  }

  // main epilogue: write d-columns to global; z<2 also deposits Y-tile in LDS.
#pragma unroll
  for (int m = 0; m < 4; ++m)
#pragma unroll
    for (int n = 0; n < 4; ++n)
#pragma unroll
      for (int r = 0; r < 4; ++r) {
        int lrow = wm + m * 16 + g4 * 4 + r;
        int lcol = wn + n * 16 + r15;
        int i = i0 + lrow, j = j0 + lcol;
        float y = acc[m][n][r] * sc;
        int b = i >> 10, s = i & 1023, h = j >> 6, d = j & 63;
        Dst[(((size_t)b * 16 + h) * SS + s) * dstride + d] = f2b(y);
        if (z < 2) {
          int c8 = (lcol >> 3) ^ (lrow & 7);
          Ys[lrow * 128 + c8 * 8 + (lcol & 7)] = f2b(y);
        }
      }

  if (z < 2) {
    const float* rel = (z == 0) ? relk : relq;
    const int cbase = (z == 0) ? 64 : 98;
    const int h0 = by * 2;
    __syncthreads();
#pragma unroll
    for (int hh = 0; hh < 2; ++hh) {
      bf16x8 bfr[3][2];
#pragma unroll
      for (int n = 0; n < 3; ++n) {
        int r = n * 16 + r15;
#pragma unroll
        for (int st = 0; st < 2; ++st) {
          union { uint32_t u[4]; bf16x8 v; } bw;
          if (r < 34) {
            const float* src = rel + (((size_t)(h0 + hh)) * 34 + r) * 64 + st * 32 + g4 * 8;
            float4 f0 = *(const float4*)src;
            float4 f1 = *(const float4*)(src + 4);
            bw.u[0] = cvtpk(f0.x, f0.y);
            bw.u[1] = cvtpk(f0.z, f0.w);
            bw.u[2] = cvtpk(f1.x, f1.y);
            bw.u[3] = cvtpk(f1.z, f1.w);
          } else {
            bw.u[0] = bw.u[1] = bw.u[2] = bw.u[3] = 0u;
          }
          bfr[n][st] = bw.v;
        }
      }

      f32x4 a2[2][3];
#pragma unroll
      for (int m2 = 0; m2 < 2; ++m2)
#pragma unroll
        for (int n = 0; n < 3; ++n) a2[m2][n] = (f32x4){0.f, 0.f, 0.f, 0.f};

#pragma unroll
      for (int m2 = 0; m2 < 2; ++m2) {
        int lrow = wave * 32 + m2 * 16 + r15;
        int c8a = (hh * 8 + 0 * 4 + g4) ^ (lrow & 7);
        int c8b = (hh * 8 + 1 * 4 + g4) ^ (lrow & 7);
        bf16x8 a0 = *(const bf16x8*)(Ys + lrow * 128 + c8a * 8);
        bf16x8 a1 = *(const bf16x8*)(Ys + lrow * 128 + c8b * 8);
#pragma unroll
        for (int n = 0; n < 3; ++n) {
          a2[m2][n] = __builtin_amdgcn_mfma_f32_16x16x32_bf16(a0, bfr[n][0], a2[m2][n], 0, 0, 0);
          a2[m2][n] = __builtin_amdgcn_mfma_f32_16x16x32_bf16(a1, bfr[n][1], a2[m2][n], 0, 0, 0);
        }
      }

      const int h = by * 2 + hh;
#pragma unroll
      for (int m2 = 0; m2 < 2; ++m2)
#pragma unroll
        for (int n = 0; n < 3; ++n) {
          int col = n * 16 + r15;
          if (col < 34) {
#pragma unroll
            for (int rr = 0; rr < 4; ++rr) {
              int i = i0 + wave * 32 + m2 * 16 + g4 * 4 + rr;
              int b = i >> 10, s = i & 1023;
              Dst[(((size_t)b * 16 + h) * SS + s) * DAUG + cbase + col] = f2b(a2[m2][n][rr]);
            }
          }
        }
    }
  }
}

// ---------------- output projection GEMM: 64x128 tile, 512 blocks (2/CU grid) ----------
__global__ __launch_bounds__(256) void gemm_out(const unsigned short* __restrict__ Oh,
                                                const unsigned short* __restrict__ Wob,
                                                float* __restrict__ Out) {
  const int n_ = blockIdx.x + 64 * blockIdx.y;
  const int o_ = (n_ & 7) * 64 + (n_ >> 3);
  const int bx = o_ & 63, by = o_ >> 6;

  __shared__ unsigned short At[2][64 * 32];    // 8KB
  __shared__ unsigned short Bt[2][128 * 32];   // 16KB

  const int tid = threadIdx.x, wave = tid >> 6, lane = tid & 63;
  const int r15 = lane & 15, g4 = lane >> 4;
  const int i0 = bx * 64, j0 = by * 128;
  const int wm = (wave >> 1) * 32, wn = (wave & 1) * 64;

  auto stage = [&](int k0, int buf) {
    {
      int i = tid, row = i >> 2, cg = i & 3;
      int gi = i0 + row, b = gi >> 10, s = gi & 1023;
      int kcol = k0 + cg * 8, h = kcol >> 6, dd = kcol & 63;
      async16(Oh + (((size_t)b * 16 + h) * SS + s) * 64 + dd, &At[buf][0] + (size_t)i * 8);
    }
#pragma unroll
    for (int c2 = 0; c2 < 2; ++c2) {
      int i = c2 * 256 + tid, row = i >> 2, cg = i & 3;
      async16(Wob + (size_t)(j0 + row) * 1024 + k0 + cg * 8, &Bt[buf][0] + (size_t)i * 8);
    }
  };

  f32x4 acc[2][4];
#pragma unroll
  for (int m = 0; m < 2; ++m)
#pragma unroll
    for (int n = 0; n < 4; ++n) acc[m][n] = (f32x4){0.f, 0.f, 0.f, 0.f};

  stage(0, 0);
  __syncthreads();

  for (int it = 0; it < 32; ++it) {
    const int cur = it & 1, nxt = cur ^ 1;
    if (it < 31) stage((it + 1) * 32, nxt);
    bf16x8 af[2], bf[4];
#pragma unroll
    for (int m = 0; m < 2; ++m)
      af[m] = *(const bf16x8*)(&At[cur][(wm + m * 16 + r15) * 32 + g4 * 8]);
#pragma unroll
    for (int n = 0; n < 4; ++n)
      bf[n] = *(const bf16x8*)(&Bt[cur][(wn + n * 16 + r15) * 32 + g4 * 8]);
    __builtin_amdgcn_s_setprio(1);
#pragma unroll
    for (int m = 0; m < 2; ++m)
#pragma unroll
      for (int n = 0; n < 4; ++n)
        acc[m][n] = __builtin_amdgcn_mfma_f32_16x16x32_bf16(af[m], bf[n], acc[m][n], 0, 0, 0);
    __builtin_amdgcn_s_setprio(0);
    __syncthreads();
  }

#pragma unroll
  for (int m = 0; m < 2; ++m)
#pragma unroll
    for (int n = 0; n < 4; ++n)
#pragma unroll
      for (int r = 0; r < 4; ++r) {
        int i = i0 + wm + m * 16 + g4 * 4 + r;
        int j = j0 + wn + n * 16 + r15;
        Out[(size_t)i * 1024 + j] = acc[m][n][r];
      }
}

// ---------------- merged pos transpose-copy + zero pad + V' build ----------------
__global__ __launch_bounds__(256) void pos_vp(unsigned short* __restrict__ Qt,
                                              unsigned short* __restrict__ Kt,
                                              const float* __restrict__ cpe,
                                              const float* __restrict__ cpp,
                                              const float* __restrict__ pe,
                                              const float* __restrict__ pp,
                                              const unsigned short* __restrict__ Vp,
                                              const float* __restrict__ relv,
                                              unsigned short* __restrict__ VpT) {
  const int z = blockIdx.z;
  unsigned short* T = z ? Kt : Qt;
  const float* Pe = z ? pe : cpe;
  const float* Pp = z ? pp : cpp;
  const int cbase = z ? 64 : 98;
  const float scale = z ? 1.0f : KAPPA;
  const int bh = blockIdx.y, h = bh & 15, s0 = blockIdx.x * 64;
  const int tid = threadIdx.x;
  __shared__ float PeL[17][65];
  __shared__ float PpL[17][65];
  __shared__ unsigned short VT[64][72];

  for (int idx = tid; idx < 17 * 64; idx += 256) {
    int r = idx >> 6, c = idx & 63;
    PeL[r][c] = Pe[((size_t)bh * 17 + r) * SS + s0 + c];
    PpL[r][c] = Pp[((size_t)bh * 17 + r) * SS + s0 + c];
  }
  __syncthreads();

  for (int idx = tid; idx < 4096; idx += 256) {
    int s = idx >> 6, j = idx & 63;
    if (j < 34) {
      float v = (j < 17) ? PeL[j][s] : PpL[j - 17][s];
      T[((size_t)bh * SS + s0 + s) * DAUG + cbase + j] = f2b(v * scale);
    } else if (j < 46) {
      T[((size_t)bh * SS + s0 + s) * DAUG + 132 + (j - 34)] = 0;
    }
  }

  if (z == 1) {
    const int d = tid & 63, sg = tid >> 6;
    float acc[16];
#pragma unroll
    for (int si = 0; si < 16; ++si) acc[si] = 0.f;
    for (int r = 0; r < 17; ++r) {
      float ve = relv[((size_t)h * 34 + r) * 64 + d];
      float vpv = relv[((size_t)h * 34 + 17 + r) * 64 + d];
#pragma unroll
      for (int si = 0; si < 16; ++si) {
        int s = sg * 16 + si;
        acc[si] += PeL[r][s] * ve + PpL[r][s] * vpv;
      }
    }
#pragma unroll
    for (int si = 0; si < 16; ++si) {
      int s = sg * 16 + si;
      float v = b2f(Vp[((size_t)bh * SS + s0 + s) * 64 + d]) + acc[si];
      VT[d][s] = f2b(v);
    }
    __syncthreads();

    for (int c = tid; c < 512; c += 256) {
      int row = c >> 3, c8 = c & 7;
      uint4 v = *(const uint4*)&VT[row][c8 * 8];
      *(uint4*)(VpT + ((size_t)bh * 64 + row) * 1024 + s0 + c8 * 8) = v;
    }
  }
}

// ---------------- flash attention v9b: DAUG=144, 52KB LDS, launch_bounds(512,4) -------
__global__ __launch_bounds__(512, 4) void flash_attn5(
    const unsigned short* __restrict__ Qt, const unsigned short* __restrict__ Kt,
    const unsigned short* __restrict__ VpT, unsigned short* __restrict__ Oh) {
  const int n_ = blockIdx.x + 8 * blockIdx.y;
  const int o_ = (n_ & 7) * 64 + (n_ >> 3);
  const int bh = o_ >> 3;
  const int q0 = (o_ & 7) * 128;
  const int tid = threadIdx.x, wave = tid >> 6, lane = tid & 63;
  const int l31 = lane & 31, hi = lane >> 5;
  const int qq = wave & 3, kvh = wave >> 2;

  // K dbuf 2x(64x144)=18432 ush + V dbuf 2x4096=8192 ush = 26624 ush = 52KB
  __shared__ unsigned short SM[26624];

  const unsigned short* Kbase = Kt + (size_t)bh * SS * DAUG;
  const unsigned short* Vbase = VpT + (size_t)bh * 64 * 1024;

  bf16x8 qf[9];
  {
    const unsigned short* Qg = Qt + ((size_t)bh * SS + q0 + qq * 32 + l31) * DAUG + hi * 8;
#pragma unroll
    for (int kk = 0; kk < 9; ++kk) qf[kk] = *(const bf16x8*)(Qg + kk * 16);
  }

  // K tile: 64 rows x 18 chunks = 1152 chunks
  auto stageK = [&](int kv0, int buf) {
    const unsigned short* Kg = Kbase + (size_t)kv0 * DAUG;
#pragma unroll
    for (int j = 0; j < 2; ++j) {
      int i = j * 512 + wave * 64 + lane;
      int row = i / 18, c = i % 18;
      async16(Kg + (size_t)row * DAUG + ksw(c, row) * 8, SM + buf * 9216 + (size_t)i * 8);
    }
    if (wave < 2) {
      int i = 1024 + wave * 64 + lane;
      int row = i / 18, c = i % 18;
      async16(Kg + (size_t)row * DAUG + ksw(c, row) * 8, SM + buf * 9216 + (size_t)i * 8);
    }
  };
  auto stageV = [&](int kv0, int buf) {
    int c = tid;
    int row = c >> 3, c8 = c & 7;
    async16(Vbase + (size_t)row * 1024 + kv0 + ((c8 ^ (row & 7)) << 3),
            SM + 18432 + buf * 4096 + (size_t)c * 8);
  };

  stageK(0, 0);
  stageV(0, 0);
  __syncthreads();

  f32x16 accO[2];
#pragma unroll
  for (int j = 0; j < 16; ++j) { accO[0][j] = 0.f; accO[1][j] = 0.f; }
  float run_m = -INFINITY, run_l = 0.f;

  const int krow = kvh * 32 + l31;

  for (int t = 0; t < 16; ++t) {
    const int cur = t & 1, nxt = cur ^ 1;
    if (t < 15) {
      stageK((t + 1) * 64, nxt);
      stageV((t + 1) * 64, nxt);
    }

    f32x16 sT;
#pragma unroll
    for (int j = 0; j < 16; ++j) sT[j] = 0.f;
    __builtin_amdgcn_s_setprio(1);
#pragma unroll
    for (int kk = 0; kk < 9; ++kk) {
      int c = 2 * kk + hi;
      bf16x8 kf = *(const bf16x8*)(SM + cur * 9216 + (size_t)krow * DAUG + ksw(c, krow) * 8);
      sT = __builtin_amdgcn_mfma_f32_32x32x16_bf16(kf, qf[kk], sT, 0, 0, 0);
    }
    __builtin_amdgcn_s_setprio(0);

    float a0 = fmaxf(fmaxf(sT[0], sT[1]), sT[2]);
    float a1 = fmaxf(fmaxf(sT[3], sT[4]), sT[5]);
    float a2 = fmaxf(fmaxf(sT[6], sT[7]), sT[8]);
    float a3 = fmaxf(fmaxf(sT[9], sT[10]), sT[11]);
    float a4 = fmaxf(fmaxf(sT[12], sT[13]), sT[14]);
    float b0 = fmaxf(fmaxf(a0, a1), a2);
    float b1 = fmaxf(fmaxf(a3, a4), sT[15]);
    float mx = fmaxf(b0, b1);
    mx = fmaxf(mx, __shfl_xor(mx, 32, 64));

    bool cond = (mx <= run_m + 8.f);
    if (!__all(cond)) {
      float mnew = fmaxf(run_m, mx);
      float corr = exp2f(run_m - mnew);
      run_m = mnew;
      run_l *= corr;
#pragma unroll
      for (int j = 0; j < 16; ++j) { accO[0][j] *= corr; accO[1][j] *= corr; }
    }
    float lsum = 0.f;
#pragma unroll
    for (int j = 0; j < 16; ++j) {
      float p = exp2f(sT[j] - run_m);
      sT[j] = p;
      lsum += p;
    }
    run_l += lsum + __shfl_xor(lsum, 32, 64);

    uint32_t w[8];
#pragma unroll
    for (int j = 0; j < 8; ++j) w[j] = cvtpk(sT[2 * j], sT[2 * j + 1]);

    bf16x8 bfrag[2];
#pragma unroll
    for (int ks = 0; ks < 2; ++ks) {
      int b = ks * 4;
      uint32_t sel_a = hi ? w[b + 0] : w[b + 2];
      uint32_t sel_b = hi ? w[b + 1] : w[b + 3];
      uint32_t x_a = (uint32_t)__shfl_xor((int)sel_a, 32, 64);
      uint32_t x_b = (uint32_t)__shfl_xor((int)sel_b, 32, 64);
      union { uint32_t u[4]; bf16x8 v; } bw;
      bw.u[0] = hi ? x_a : w[b + 0];
      bw.u[1] = hi ? x_b : w[b + 1];
      bw.u[2] = hi ? w[b + 2] : x_a;
      bw.u[3] = hi ? w[b + 3] : x_b;
      bfrag[ks] = bw.v;
    }

    __builtin_amdgcn_s_setprio(1);
#pragma unroll
    for (int dt = 0; dt < 2; ++dt) {
      int vrow = dt * 32 + l31;
#pragma unroll
      for (int ks = 0; ks < 2; ++ks) {
        int c = kvh * 4 + ks * 2 + hi;
        bf16x8 vf = *(const bf16x8*)(SM + 18432 + cur * 4096 + (size_t)vrow * 64 +
                                     ((c ^ (vrow & 7)) << 3));
        accO[dt] = __builtin_amdgcn_mfma_f32_32x32x16_bf16(vf, bfrag[ks], accO[dt], 0, 0, 0);
      }
    }
    __builtin_amdgcn_s_setprio(0);

    __syncthreads();
  }

  float* SC = (float*)SM;
  float* Ml = SC + 8192;
  float* Ll = SC + 8320;
  uint32_t* OT = (uint32_t*)(SC + 8448);

  if (kvh == 1) {
#pragma unroll
    for (int dt = 0; dt < 2; ++dt)
#pragma unroll
      for (int j = 0; j < 16; ++j) {
        int d = (j & 3) + 8 * (j >> 2) + 4 * hi + 32 * dt;
        SC[qq * 2048 + d * 32 + l31] = accO[dt][j];
      }
    if (hi == 0) {
      Ml[qq * 32 + l31] = run_m;
      Ll[qq * 32 + l31] = run_l;
    }
  }
  __syncthreads();
  if (kvh == 0) {
    float m1 = Ml[qq * 32 + l31], l1v = Ll[qq * 32 + l31];
    float M = fmaxf(run_m, m1);
    float c0 = exp2f(run_m - M), c1 = exp2f(m1 - M);
    float inv = 1.f / (run_l * c0 + l1v * c1);
#pragma unroll
    for (int dt = 0; dt < 2; ++dt)
#pragma unroll
      for (int j = 0; j < 16; j += 2) {
        int d = (j & 3) + 8 * (j >> 2) + 4 * hi + 32 * dt;
        float o0 = (accO[dt][j] * c0 + SC[qq * 2048 + d * 32 + l31] * c1) * inv;
        float o1 = (accO[dt][j + 1] * c0 + SC[qq * 2048 + (d + 1) * 32 + l31] * c1) * inv;
        OT[(qq * 32 + l31) * 33 + (d >> 1)] = pk2(o0, o1);
      }
  }
  __syncthreads();
  for (int c = tid; c < 1024; c += 512) {
    int row = c >> 3, ch = c & 7;
    uint4 v;
    v.x = OT[row * 33 + ch * 4 + 0];
    v.y = OT[row * 33 + ch * 4 + 1];
    v.z = OT[row * 33 + ch * 4 + 2];
    v.w = OT[row * 33 + ch * 4 + 3];
    *(uint4*)(Oh + ((size_t)bh * SS + q0 + row) * 64 + ch * 8) = v;
  }
}

extern "C" void kernel_launch(void* const* d_in, const int* in_sizes, int n_in,
                              void* d_out, int out_size, void* d_ws, size_t ws_size,
                              hipStream_t stream) {
  const float* query = (const float*)d_in[0];
  const float* key = (const float*)d_in[1];
  const float* value = (const float*)d_in[2];
  const float* pe = (const float*)d_in[3];
  const float* pp = (const float*)d_in[4];
  const float* cpe = (const float*)d_in[5];
  const float* cpp = (const float*)d_in[6];
  const float* relq = (const float*)d_in[7];
  const float* relk = (const float*)d_in[8];
  const float* relv = (const float*)d_in[9];
  const float* Wq = (const float*)d_in[10];
  const float* Wk = (const float*)d_in[11];
  const float* Wv = (const float*)d_in[12];
  const float* Wo = (const float*)d_in[13];
  float* out = (float*)d_out;
  char* ws = (char*)d_ws;

  unsigned short* Xq = (unsigned short*)(ws + 0);
  unsigned short* Xk = (unsigned short*)(ws + 8388608);
  unsigned short* Xv = (unsigned short*)(ws + 16777216);
  unsigned short* Wqb = (unsigned short*)(ws + 25165824);
  unsigned short* Wkb = (unsigned short*)(ws + 27262976);
  unsigned short* Wvb = (unsigned short*)(ws + 29360128);
  unsigned short* Wob = (unsigned short*)(ws + 31457280);
  unsigned short* Qt = (unsigned short*)(ws + 33554432);
  unsigned short* Kt = (unsigned short*)(ws + 54525952);
  unsigned short* Vp = (unsigned short*)(ws + 75497472);
  unsigned short* Oh = (unsigned short*)(ws + 0);         // alias Xq (dead after proj)
  unsigned short* VpT = (unsigned short*)(ws + 8388608);  // alias Xk/Xv (dead after proj)

  convert7<<<dim3(1024, 7, 1), 256, 0, stream>>>(query, key, value, Wq, Wk, Wv, Wo, Xq, Xk, Xv,
                                                 Wqb, Wkb, Wvb, Wob);
  proj_qkv<<<dim3(32, 8, 3), 256, 0, stream>>>(Xq, Xk, Xv, Wqb, Wkb, Wvb, Qt, Kt, Vp, relk, relq);
  pos_vp<<<dim3(16, 64, 2), 256, 0, stream>>>(Qt, Kt, cpe, cpp, pe, pp, Vp, relv, VpT);
  flash_attn5<<<dim3(8, 64, 1), 512, 0, stream>>>(Qt, Kt, VpT, Oh);
  gemm_out<<<dim3(64, 8, 1), 256, 0, stream>>>(Oh, Wob, out);
}

// Round 20
// 152.094 us; speedup vs baseline: 1.0197x; 1.0197x over previous
//
#include <hip/hip_runtime.h>
#include <hip/hip_bf16.h>
#include <stdint.h>

typedef float f32x4 __attribute__((ext_vector_type(4)));
typedef float f32x16 __attribute__((ext_vector_type(16)));
typedef __bf16 bf16x8 __attribute__((ext_vector_type(8)));

#define NBH 64      // B*H
#define SS 1024     // SQ == SKV
#define DAUG 144    // augmented head dim 132 padded to 144
#define KAPPA 0.18033688011104293f  // 0.125 * log2(e), folded into Q~

static __device__ __forceinline__ unsigned short f2b(float f) {
  union { float f; uint32_t u; } v; v.f = f;
  return (unsigned short)((v.u + 0x7fffu + ((v.u >> 16) & 1u)) >> 16);
}
static __device__ __forceinline__ float b2f(unsigned short s) {
  union { uint32_t u; float f; } v; v.u = ((uint32_t)s) << 16;
  return v.f;
}
static __device__ __forceinline__ uint32_t pk2(float a, float b) {
  return (uint32_t)f2b(a) | ((uint32_t)f2b(b) << 16);
}
// HW packed f32->bf16 (RTNE), 1 instr (no builtin on gfx950 - T12 recipe)
static __device__ __forceinline__ uint32_t cvtpk(float lo, float hi) {
  uint32_t r;
  asm("v_cvt_pk_bf16_f32 %0, %1, %2" : "=v"(r) : "v"(lo), "v"(hi));
  return r;
}

static __device__ __forceinline__ void async16(const void* g, void* l) {
  __builtin_amdgcn_global_load_lds(
      (const __attribute__((address_space(1))) uint32_t*)g,
      (__attribute__((address_space(3))) uint32_t*)l, 16, 0, 0);
}

// K-tile chunk swizzle (18 16B-chunks per 144-elem row)
static __device__ __forceinline__ int ksw(int c, int row) {
  return (c < 16) ? (c ^ (row & 7)) : (16 + ((c & 1) ^ (row & 1)));
}

// ---------------- f32 -> bf16 conversion for 7 tensors ----------------
__global__ void convert7(const float* q, const float* k, const float* v,
                         const float* wq, const float* wk, const float* wv, const float* wo,
                         unsigned short* xq, unsigned short* xk, unsigned short* xv,
                         unsigned short* bwq, unsigned short* bwk, unsigned short* bwv,
                         unsigned short* bwo) {
  const float* s; unsigned short* d; int n;
  switch (blockIdx.y) {
    case 0: s = q;  d = xq;  n = 4194304; break;
    case 1: s = k;  d = xk;  n = 4194304; break;
    case 2: s = v;  d = xv;  n = 4194304; break;
    case 3: s = wq; d = bwq; n = 1048576; break;
    case 4: s = wk; d = bwk; n = 1048576; break;
    case 5: s = wv; d = bwv; n = 1048576; break;
    default: s = wo; d = bwo; n = 1048576; break;
  }
  int n4 = n >> 2;
  for (int i = blockIdx.x * blockDim.x + threadIdx.x; i < n4; i += gridDim.x * blockDim.x) {
    float4 f = ((const float4*)s)[i];
    uint2 o;
    o.x = cvtpk(f.x, f.y);
    o.y = cvtpk(f.z, f.w);
    ((uint2*)d)[i] = o;
  }
}

// ---------------- QKV projection GEMM + fused rank-34 augmentation (R12 winner) -------
__global__ __launch_bounds__(256) void proj_qkv(
    const unsigned short* __restrict__ Xq, const unsigned short* __restrict__ Xk,
    const unsigned short* __restrict__ Xv, const unsigned short* __restrict__ Wqb,
    const unsigned short* __restrict__ Wkb, const unsigned short* __restrict__ Wvb,
    unsigned short* __restrict__ Qt, unsigned short* __restrict__ Kt,
    unsigned short* __restrict__ Vp, const float* __restrict__ relk,
    const float* __restrict__ relq) {
  const int n_ = blockIdx.x + 32 * (blockIdx.y + 8 * blockIdx.z);
  const int o_ = (n_ & 7) * 96 + (n_ >> 3);
  const int bx = o_ & 31, by = (o_ >> 5) & 7, z = o_ >> 8;

  const unsigned short* A = (z == 0) ? Xq : (z == 1) ? Xk : Xv;
  const unsigned short* Bw = (z == 0) ? Wqb : (z == 1) ? Wkb : Wvb;
  unsigned short* Dst = (z == 0) ? Qt : (z == 1) ? Kt : Vp;
  const int dstride = (z == 2) ? 64 : DAUG;
  const float sc = (z == 0) ? KAPPA : 1.0f;

  __shared__ unsigned short SMEM[16384];  // dbuf At/Bt; after K-loop: Ys 128x128
  unsigned short* AtB = SMEM;
  unsigned short* BtB = SMEM + 8192;
  unsigned short* Ys = SMEM;

  const int tid = threadIdx.x, wave = tid >> 6, lane = tid & 63;
  const int r15 = lane & 15, g4 = lane >> 4;
  const int i0 = bx * 128, j0 = by * 128;
  const int wm = (wave >> 1) * 64, wn = (wave & 1) * 64;

  auto stage = [&](int k0, int buf) {
#pragma unroll
    for (int c = 0; c < 2; ++c) {
      int ch = (wave * 2 + c) * 64 + lane;
      int row = ch >> 2, cg = ch & 3;
      async16(A + (size_t)(i0 + row) * 1024 + k0 + cg * 8, AtB + buf * 4096 + (wave * 2 + c) * 512);
      async16(Bw + (size_t)(j0 + row) * 1024 + k0 + cg * 8, BtB + buf * 4096 + (wave * 2 + c) * 512);
    }
  };

  f32x4 acc[4][4];
#pragma unroll
  for (int m = 0; m < 4; ++m)
#pragma unroll
    for (int n = 0; n < 4; ++n) acc[m][n] = (f32x4){0.f, 0.f, 0.f, 0.f};

  stage(0, 0);
  __syncthreads();

  for (int it = 0; it < 32; ++it) {
    const int cur = it & 1, nxt = cur ^ 1;
    if (it < 31) stage((it + 1) * 32, nxt);
    bf16x8 af[4], bf[4];
#pragma unroll
    for (int m = 0; m < 4; ++m)
      af[m] = *(const bf16x8*)(AtB + cur * 4096 + (wm + m * 16 + r15) * 32 + g4 * 8);
#pragma unroll
    for (int n = 0; n < 4; ++n)
      bf[n] = *(const bf16x8*)(BtB + cur * 4096 + (wn + n * 16 + r15) * 32 + g4 * 8);
    __builtin_amdgcn_s_setprio(1);
#pragma unroll
    for (int m = 0; m < 4; ++m)
#pragma unroll
      for (int n = 0; n < 4; ++n)
        acc[m][n] = __builtin_amdgcn_mfma_f32_16x16x32_bf16(af[m], bf[n], acc[m][n], 0, 0, 0);
    __builtin_amdgcn_s_setprio(0);
    __syncthreads();
  }

#pragma unroll
  for (int m = 0; m < 4; ++m)
#pragma unroll
    for (int n = 0; n < 4; ++n)
#pragma unroll
      for (int r = 0; r < 4; ++r) {
        int lrow = wm + m * 16 + g4 * 4 + r;
        int lcol = wn + n * 16 + r15;
        int i = i0 + lrow, j = j0 + lcol;
        float y = acc[m][n][r] * sc;
        int b = i >> 10, s = i & 1023, h = j >> 6, d = j & 63;
        Dst[(((size_t)b * 16 + h) * SS + s) * dstride + d] = f2b(y);
        if (z < 2) {
          int c8 = (lcol >> 3) ^ (lrow & 7);
          Ys[lrow * 128 + c8 * 8 + (lcol & 7)] = f2b(y);
        }
      }

  if (z < 2) {
    const float* rel = (z == 0) ? relk : relq;
    const int cbase = (z == 0) ? 64 : 98;
    const int h0 = by * 2;
    __syncthreads();
#pragma unroll
    for (int hh = 0; hh < 2; ++hh) {
      bf16x8 bfr[3][2];
#pragma unroll
      for (int n = 0; n < 3; ++n) {
        int r = n * 16 + r15;
#pragma unroll
        for (int st = 0; st < 2; ++st) {
          union { uint32_t u[4]; bf16x8 v; } bw;
          if (r < 34) {
            const float* src = rel + (((size_t)(h0 + hh)) * 34 + r) * 64 + st * 32 + g4 * 8;
            float4 f0 = *(const float4*)src;
            float4 f1 = *(const float4*)(src + 4);
            bw.u[0] = cvtpk(f0.x, f0.y);
            bw.u[1] = cvtpk(f0.z, f0.w);
            bw.u[2] = cvtpk(f1.x, f1.y);
            bw.u[3] = cvtpk(f1.z, f1.w);
          } else {
            bw.u[0] = bw.u[1] = bw.u[2] = bw.u[3] = 0u;
          }
          bfr[n][st] = bw.v;
        }
      }

      f32x4 a2[2][3];
#pragma unroll
      for (int m2 = 0; m2 < 2; ++m2)
#pragma unroll
        for (int n = 0; n < 3; ++n) a2[m2][n] = (f32x4){0.f, 0.f, 0.f, 0.f};

#pragma unroll
      for (int m2 = 0; m2 < 2; ++m2) {
        int lrow = wave * 32 + m2 * 16 + r15;
        int c8a = (hh * 8 + 0 * 4 + g4) ^ (lrow & 7);
        int c8b = (hh * 8 + 1 * 4 + g4) ^ (lrow & 7);
        bf16x8 a0 = *(const bf16x8*)(Ys + lrow * 128 + c8a * 8);
        bf16x8 a1 = *(const bf16x8*)(Ys + lrow * 128 + c8b * 8);
#pragma unroll
        for (int n = 0; n < 3; ++n) {
          a2[m2][n] = __builtin_amdgcn_mfma_f32_16x16x32_bf16(a0, bfr[n][0], a2[m2][n], 0, 0, 0);
          a2[m2][n] = __builtin_amdgcn_mfma_f32_16x16x32_bf16(a1, bfr[n][1], a2[m2][n], 0, 0, 0);
        }
      }

      const int h = by * 2 + hh;
#pragma unroll
      for (int m2 = 0; m2 < 2; ++m2)
#pragma unroll
        for (int n = 0; n < 3; ++n) {
          int col = n * 16 + r15;
          if (col < 34) {
#pragma unroll
            for (int rr = 0; rr < 4; ++rr) {
              int i = i0 + wave * 32 + m2 * 16 + g4 * 4 + rr;
              int b = i >> 10, s = i & 1023;
              Dst[(((size_t)b * 16 + h) * SS + s) * DAUG + cbase + col] = f2b(a2[m2][n][rr]);
            }
          }
        }
    }
  }
}

// ---------------- output projection GEMM: 64x128 tile, 512 blocks (2/CU grid) ----------
__global__ __launch_bounds__(256) void gemm_out(const unsigned short* __restrict__ Oh,
                                                const unsigned short* __restrict__ Wob,
                                                float* __restrict__ Out) {
  const int n_ = blockIdx.x + 64 * blockIdx.y;
  const int o_ = (n_ & 7) * 64 + (n_ >> 3);
  const int bx = o_ & 63, by = o_ >> 6;

  __shared__ unsigned short At[2][64 * 32];    // 8KB
  __shared__ unsigned short Bt[2][128 * 32];   // 16KB

  const int tid = threadIdx.x, wave = tid >> 6, lane = tid & 63;
  const int r15 = lane & 15, g4 = lane >> 4;
  const int i0 = bx * 64, j0 = by * 128;
  const int wm = (wave >> 1) * 32, wn = (wave & 1) * 64;

  auto stage = [&](int k0, int buf) {
    {
      int i = tid, row = i >> 2, cg = i & 3;
      int gi = i0 + row, b = gi >> 10, s = gi & 1023;
      int kcol = k0 + cg * 8, h = kcol >> 6, dd = kcol & 63;
      async16(Oh + (((size_t)b * 16 + h) * SS + s) * 64 + dd, &At[buf][0] + (size_t)i * 8);
    }
#pragma unroll
    for (int c2 = 0; c2 < 2; ++c2) {
      int i = c2 * 256 + tid, row = i >> 2, cg = i & 3;
      async16(Wob + (size_t)(j0 + row) * 1024 + k0 + cg * 8, &Bt[buf][0] + (size_t)i * 8);
    }
  };

  f32x4 acc[2][4];
#pragma unroll
  for (int m = 0; m < 2; ++m)
#pragma unroll
    for (int n = 0; n < 4; ++n) acc[m][n] = (f32x4){0.f, 0.f, 0.f, 0.f};

  stage(0, 0);
  __syncthreads();

  for (int it = 0; it < 32; ++it) {
    const int cur = it & 1, nxt = cur ^ 1;
    if (it < 31) stage((it + 1) * 32, nxt);
    bf16x8 af[2], bf[4];
#pragma unroll
    for (int m = 0; m < 2; ++m)
      af[m] = *(const bf16x8*)(&At[cur][(wm + m * 16 + r15) * 32 + g4 * 8]);
#pragma unroll
    for (int n = 0; n < 4; ++n)
      bf[n] = *(const bf16x8*)(&Bt[cur][(wn + n * 16 + r15) * 32 + g4 * 8]);
    __builtin_amdgcn_s_setprio(1);
#pragma unroll
    for (int m = 0; m < 2; ++m)
#pragma unroll
      for (int n = 0; n < 4; ++n)
        acc[m][n] = __builtin_amdgcn_mfma_f32_16x16x32_bf16(af[m], bf[n], acc[m][n], 0, 0, 0);
    __builtin_amdgcn_s_setprio(0);
    __syncthreads();
  }

#pragma unroll
  for (int m = 0; m < 2; ++m)
#pragma unroll
    for (int n = 0; n < 4; ++n)
#pragma unroll
      for (int r = 0; r < 4; ++r) {
        int i = i0 + wm + m * 16 + g4 * 4 + r;
        int j = j0 + wn + n * 16 + r15;
        Out[(size_t)i * 1024 + j] = acc[m][n][r];
      }
}

// ---------------- merged pos transpose-copy + zero pad + V' build ----------------
__global__ __launch_bounds__(256) void pos_vp(unsigned short* __restrict__ Qt,
                                              unsigned short* __restrict__ Kt,
                                              const float* __restrict__ cpe,
                                              const float* __restrict__ cpp,
                                              const float* __restrict__ pe,
                                              const float* __restrict__ pp,
                                              const unsigned short* __restrict__ Vp,
                                              const float* __restrict__ relv,
                                              unsigned short* __restrict__ VpT) {
  const int z = blockIdx.z;
  unsigned short* T = z ? Kt : Qt;
  const float* Pe = z ? pe : cpe;
  const float* Pp = z ? pp : cpp;
  const int cbase = z ? 64 : 98;
  const float scale = z ? 1.0f : KAPPA;
  const int bh = blockIdx.y, h = bh & 15, s0 = blockIdx.x * 64;
  const int tid = threadIdx.x;
  __shared__ float PeL[17][65];
  __shared__ float PpL[17][65];
  __shared__ unsigned short VT[64][72];

  for (int idx = tid; idx < 17 * 64; idx += 256) {
    int r = idx >> 6, c = idx & 63;
    PeL[r][c] = Pe[((size_t)bh * 17 + r) * SS + s0 + c];
    PpL[r][c] = Pp[((size_t)bh * 17 + r) * SS + s0 + c];
  }
  __syncthreads();

  for (int idx = tid; idx < 4096; idx += 256) {
    int s = idx >> 6, j = idx & 63;
    if (j < 34) {
      float v = (j < 17) ? PeL[j][s] : PpL[j - 17][s];
      T[((size_t)bh * SS + s0 + s) * DAUG + cbase + j] = f2b(v * scale);
    } else if (j < 46) {
      T[((size_t)bh * SS + s0 + s) * DAUG + 132 + (j - 34)] = 0;
    }
  }

  if (z == 1) {
    const int d = tid & 63, sg = tid >> 6;
    float acc[16];
#pragma unroll
    for (int si = 0; si < 16; ++si) acc[si] = 0.f;
    for (int r = 0; r < 17; ++r) {
      float ve = relv[((size_t)h * 34 + r) * 64 + d];
      float vpv = relv[((size_t)h * 34 + 17 + r) * 64 + d];
#pragma unroll
      for (int si = 0; si < 16; ++si) {
        int s = sg * 16 + si;
        acc[si] += PeL[r][s] * ve + PpL[r][s] * vpv;
      }
    }
#pragma unroll
    for (int si = 0; si < 16; ++si) {
      int s = sg * 16 + si;
      float v = b2f(Vp[((size_t)bh * SS + s0 + s) * 64 + d]) + acc[si];
      VT[d][s] = f2b(v);
    }
    __syncthreads();

    for (int c = tid; c < 512; c += 256) {
      int row = c >> 3, c8 = c & 7;
      uint4 v = *(const uint4*)&VT[row][c8 * 8];
      *(uint4*)(VpT + ((size_t)bh * 64 + row) * 1024 + s0 + c8 * 8) = v;
    }
  }
}

// ---------------- flash attention v9b: DAUG=144, 52KB LDS, launch_bounds(512,4) -------
__global__ __launch_bounds__(512, 4) void flash_attn5(
    const unsigned short* __restrict__ Qt, const unsigned short* __restrict__ Kt,
    const unsigned short* __restrict__ VpT, unsigned short* __restrict__ Oh) {
  const int n_ = blockIdx.x + 8 * blockIdx.y;
  const int o_ = (n_ & 7) * 64 + (n_ >> 3);
  const int bh = o_ >> 3;
  const int q0 = (o_ & 7) * 128;
  const int tid = threadIdx.x, wave = tid >> 6, lane = tid & 63;
  const int l31 = lane & 31, hi = lane >> 5;
  const int qq = wave & 3, kvh = wave >> 2;

  // K dbuf 2x(64x144)=18432 ush + V dbuf 2x4096=8192 ush = 26624 ush = 52KB
  __shared__ unsigned short SM[26624];

  const unsigned short* Kbase = Kt + (size_t)bh * SS * DAUG;
  const unsigned short* Vbase = VpT + (size_t)bh * 64 * 1024;

  bf16x8 qf[9];
  {
    const unsigned short* Qg = Qt + ((size_t)bh * SS + q0 + qq * 32 + l31) * DAUG + hi * 8;
#pragma unroll
    for (int kk = 0; kk < 9; ++kk) qf[kk] = *(const bf16x8*)(Qg + kk * 16);
  }

  // K tile: 64 rows x 18 chunks = 1152 chunks
  auto stageK = [&](int kv0, int buf) {
    const unsigned short* Kg = Kbase + (size_t)kv0 * DAUG;
#pragma unroll
    for (int j = 0; j < 2; ++j) {
      int i = j * 512 + wave * 64 + lane;
      int row = i / 18, c = i % 18;
      async16(Kg + (size_t)row * DAUG + ksw(c, row) * 8, SM + buf * 9216 + (size_t)i * 8);
    }
    if (wave < 2) {
      int i = 1024 + wave * 64 + lane;
      int row = i / 18, c = i % 18;
      async16(Kg + (size_t)row * DAUG + ksw(c, row) * 8, SM + buf * 9216 + (size_t)i * 8);
    }
  };
  auto stageV = [&](int kv0, int buf) {
    int c = tid;
    int row = c >> 3, c8 = c & 7;
    async16(Vbase + (size_t)row * 1024 + kv0 + ((c8 ^ (row & 7)) << 3),
            SM + 18432 + buf * 4096 + (size_t)c * 8);
  };

  stageK(0, 0);
  stageV(0, 0);
  __syncthreads();

  f32x16 accO[2];
#pragma unroll
  for (int j = 0; j < 16; ++j) { accO[0][j] = 0.f; accO[1][j] = 0.f; }
  float run_m = -INFINITY, run_l = 0.f;

  const int krow = kvh * 32 + l31;

  for (int t = 0; t < 16; ++t) {
    const int cur = t & 1, nxt = cur ^ 1;
    if (t < 15) {
      stageK((t + 1) * 64, nxt);
      stageV((t + 1) * 64, nxt);
    }

    f32x16 sT;
#pragma unroll
    for (int j = 0; j < 16; ++j) sT[j] = 0.f;
    __builtin_amdgcn_s_setprio(1);
#pragma unroll
    for (int kk = 0; kk < 9; ++kk) {
      int c = 2 * kk + hi;
      bf16x8 kf = *(const bf16x8*)(SM + cur * 9216 + (size_t)krow * DAUG + ksw(c, krow) * 8);
      sT = __builtin_amdgcn_mfma_f32_32x32x16_bf16(kf, qf[kk], sT, 0, 0, 0);
    }
    __builtin_amdgcn_s_setprio(0);

    float a0 = fmaxf(fmaxf(sT[0], sT[1]), sT[2]);
    float a1 = fmaxf(fmaxf(sT[3], sT[4]), sT[5]);
    float a2 = fmaxf(fmaxf(sT[6], sT[7]), sT[8]);
    float a3 = fmaxf(fmaxf(sT[9], sT[10]), sT[11]);
    float a4 = fmaxf(fmaxf(sT[12], sT[13]), sT[14]);
    float b0 = fmaxf(fmaxf(a0, a1), a2);
    float b1 = fmaxf(fmaxf(a3, a4), sT[15]);
    float mx = fmaxf(b0, b1);
    mx = fmaxf(mx, __shfl_xor(mx, 32, 64));

    bool cond = (mx <= run_m + 8.f);
    if (!__all(cond)) {
      float mnew = fmaxf(run_m, mx);
      float corr = exp2f(run_m - mnew);
      run_m = mnew;
      run_l *= corr;
#pragma unroll
      for (int j = 0; j < 16; ++j) { accO[0][j] *= corr; accO[1][j] *= corr; }
    }
    float lsum = 0.f;
#pragma unroll
    for (int j = 0; j < 16; ++j) {
      float p = exp2f(sT[j] - run_m);
      sT[j] = p;
      lsum += p;
    }
    run_l += lsum + __shfl_xor(lsum, 32, 64);

    uint32_t w[8];
#pragma unroll
    for (int j = 0; j < 8; ++j) w[j] = cvtpk(sT[2 * j], sT[2 * j + 1]);

    bf16x8 bfrag[2];
#pragma unroll
    for (int ks = 0; ks < 2; ++ks) {
      int b = ks * 4;
      uint32_t sel_a = hi ? w[b + 0] : w[b + 2];
      uint32_t sel_b = hi ? w[b + 1] : w[b + 3];
      uint32_t x_a = (uint32_t)__shfl_xor((int)sel_a, 32, 64);
      uint32_t x_b = (uint32_t)__shfl_xor((int)sel_b, 32, 64);
      union { uint32_t u[4]; bf16x8 v; } bw;
      bw.u[0] = hi ? x_a : w[b + 0];
      bw.u[1] = hi ? x_b : w[b + 1];
      bw.u[2] = hi ? w[b + 2] : x_a;
      bw.u[3] = hi ? w[b + 3] : x_b;
      bfrag[ks] = bw.v;
    }

    __builtin_amdgcn_s_setprio(1);
#pragma unroll
    for (int dt = 0; dt < 2; ++dt) {
      int vrow = dt * 32 + l31;
#pragma unroll
      for (int ks = 0; ks < 2; ++ks) {
        int c = kvh * 4 + ks * 2 + hi;
        bf16x8 vf = *(const bf16x8*)(SM + 18432 + cur * 4096 + (size_t)vrow * 64 +
                                     ((c ^ (vrow & 7)) << 3));
        accO[dt] = __builtin_amdgcn_mfma_f32_32x32x16_bf16(vf, bfrag[ks], accO[dt], 0, 0, 0);
      }
    }
    __builtin_amdgcn_s_setprio(0);

    __syncthreads();
  }

  float* SC = (float*)SM;
  float* Ml = SC + 8192;
  float* Ll = SC + 8320;
  uint32_t* OT = (uint32_t*)(SC + 8448);

  if (kvh == 1) {
#pragma unroll
    for (int dt = 0; dt < 2; ++dt)
#pragma unroll
      for (int j = 0; j < 16; ++j) {
        int d = (j & 3) + 8 * (j >> 2) + 4 * hi + 32 * dt;
        SC[qq * 2048 + d * 32 + l31] = accO[dt][j];
      }
    if (hi == 0) {
      Ml[qq * 32 + l31] = run_m;
      Ll[qq * 32 + l31] = run_l;
    }
  }
  __syncthreads();
  if (kvh == 0) {
    float m1 = Ml[qq * 32 + l31], l1v = Ll[qq * 32 + l31];
    float M = fmaxf(run_m, m1);
    float c0 = exp2f(run_m - M), c1 = exp2f(m1 - M);
    float inv = 1.f / (run_l * c0 + l1v * c1);
#pragma unroll
    for (int dt = 0; dt < 2; ++dt)
#pragma unroll
      for (int j = 0; j < 16; j += 2) {
        int d = (j & 3) + 8 * (j >> 2) + 4 * hi + 32 * dt;
        float o0 = (accO[dt][j] * c0 + SC[qq * 2048 + d * 32 + l31] * c1) * inv;
        float o1 = (accO[dt][j + 1] * c0 + SC[qq * 2048 + (d + 1) * 32 + l31] * c1) * inv;
        OT[(qq * 32 + l31) * 33 + (d >> 1)] = pk2(o0, o1);
      }
  }
  __syncthreads();
  for (int c = tid; c < 1024; c += 512) {
    int row = c >> 3, ch = c & 7;
    uint4 v;
    v.x = OT[row * 33 + ch * 4 + 0];
    v.y = OT[row * 33 + ch * 4 + 1];
    v.z = OT[row * 33 + ch * 4 + 2];
    v.w = OT[row * 33 + ch * 4 + 3];
    *(uint4*)(Oh + ((size_t)bh * SS + q0 + row) * 64 + ch * 8) = v;
  }
}

extern "C" void kernel_launch(void* const* d_in, const int* in_sizes, int n_in,
                              void* d_out, int out_size, void* d_ws, size_t ws_size,
                              hipStream_t stream) {
  const float* query = (const float*)d_in[0];
  const float* key = (const float*)d_in[1];
  const float* value = (const float*)d_in[2];
  const float* pe = (const float*)d_in[3];
  const float* pp = (const float*)d_in[4];
  const float* cpe = (const float*)d_in[5];
  const float* cpp = (const float*)d_in[6];
  const float* relq = (const float*)d_in[7];
  const float* relk = (const float*)d_in[8];
  const float* relv = (const float*)d_in[9];
  const float* Wq = (const float*)d_in[10];
  const float* Wk = (const float*)d_in[11];
  const float* Wv = (const float*)d_in[12];
  const float* Wo = (const float*)d_in[13];
  float* out = (float*)d_out;
  char* ws = (char*)d_ws;

  unsigned short* Xq = (unsigned short*)(ws + 0);
  unsigned short* Xk = (unsigned short*)(ws + 8388608);
  unsigned short* Xv = (unsigned short*)(ws + 16777216);
  unsigned short* Wqb = (unsigned short*)(ws + 25165824);
  unsigned short* Wkb = (unsigned short*)(ws + 27262976);
  unsigned short* Wvb = (unsigned short*)(ws + 29360128);
  unsigned short* Wob = (unsigned short*)(ws + 31457280);
  unsigned short* Qt = (unsigned short*)(ws + 33554432);
  unsigned short* Kt = (unsigned short*)(ws + 54525952);
  unsigned short* Vp = (unsigned short*)(ws + 75497472);
  unsigned short* Oh = (unsigned short*)(ws + 0);         // alias Xq (dead after proj)
  unsigned short* VpT = (unsigned short*)(ws + 8388608);  // alias Xk/Xv (dead after proj)

  convert7<<<dim3(1024, 7, 1), 256, 0, stream>>>(query, key, value, Wq, Wk, Wv, Wo, Xq, Xk, Xv,
                                                 Wqb, Wkb, Wvb, Wob);
  proj_qkv<<<dim3(32, 8, 3), 256, 0, stream>>>(Xq, Xk, Xv, Wqb, Wkb, Wvb, Qt, Kt, Vp, relk, relq);
  pos_vp<<<dim3(16, 64, 2), 256, 0, stream>>>(Qt, Kt, cpe, cpp, pe, pp, Vp, relv, VpT);
  flash_attn5<<<dim3(8, 64, 1), 512, 0, stream>>>(Qt, Kt, VpT, Oh);
  gemm_out<<<dim3(64, 8, 1), 256, 0, stream>>>(Oh, Wob, out);
}